// Round 4
// baseline (218.358 us; speedup 1.0000x reference)
//
#include <hip/hip_runtime.h>
#include <cstdint>

#define GH 10
#define GW 10

// Round 9 (plan C): board-in-LDS, zero block barriers, lean registers.
// Post-mortems: r7 (no LDS, strided float2) ~50us: wave-independent but
// ~1600 cache-line touches/wave on loads. r3 (chunked LDS + barriers) 81us:
// VGPR_Count=52 proves vv[50] lived in AGPRs -> ~150 v_accvgpr moves/thread
// (the hidden 2x VALU inflation seen since r0), plus 8 block barriers.
// Fix: each wave stages its OWN 32 samples into a wave-private 12.8KB LDS
// slice (coalesced float4 reg-staging; DS ops of a wave are in-order, so no
// __syncthreads anywhere in the hot path). Compute STREAMS the board from
// LDS twice (pass1 keeps only sums+masks; S_T pass re-streams after the
// fill) -> no 50-float live range, no AGPR toll, rs/re/rn stay LDS-hot.
// Fill/argmin/epilogue identical to r3; S_T uses precomputed 5-bit fields
// (same bits, fewer VALU). Occupancy stays LDS-bound at 12 waves/CU.
__global__ __launch_bounds__(256, 4) void custom_loss_kernel(
    const float* __restrict__ result,
    const int* __restrict__ points,
    float* __restrict__ out,
    int B)
{
    __shared__ float lds[4 * 3200];           // 4 wave-private 12.8KB slices
    __shared__ float wsum[4];
    const int tix = threadIdx.x;
    const int lane = tix & 63;
    const int wid = tix >> 6;
    const int h = tix & 1;                    // half: rows 5h..5h+4
    const int t = lane >> 1;                  // sample within wave (0..31)

    const int s = blockIdx.x * 128 + wid * 32 + t;
    float* __restrict__ myLds = lds + wid * 3200;

    // ---- wave-private staging: 32 samples = 800 float4, fully coalesced ----
    {
        const size_t wb4 = ((size_t)blockIdx.x * 128 + wid * 32) * 25;
        const size_t total4 = (size_t)B * 25;
        const float4* __restrict__ g4 = (const float4*)result;
        float4* l4 = (float4*)myLds;
        float4 st[13];
#pragma unroll
        for (int k = 0; k < 13; ++k) {
            const int off = k * 64 + lane;    // k=12: lanes 0..31 only
            if ((k < 12 || lane < 32) && (wb4 + off < total4))
                st[k] = g4[wb4 + off];
        }
#pragma unroll
        for (int k = 0; k < 13; ++k) {
            const int off = k * 64 + lane;
            if ((k < 12 || lane < 32) && (wb4 + off < total4))
                l4[off] = st[k];
        }
    }
    __threadfence_block();                    // cheap insurance: order DS ops
                                              // (same-wave DS is in-order; no
                                              // cross-wave sharing -> no bar)

    float loss = 0.f;
    if (s < B) {
        const int4 p = ((const int4*)points)[s];
        const int p0y = p.x, p0x = p.y, p1y = p.z, p1x = p.w;
        const int dy0 = abs(p0y - p1y), dx0 = abs(p0x - p1x);
        const int base0 = dy0 + dx0;
        const int idx0 = p0y * GW + p0x;
        const int idx1 = p1y * GW + p1x;

        const float* __restrict__ sp = myLds + t * 100;
        const float rs = sp[idx0];            // LDS gathers, board resident
        const float re = sp[idx1];

        float adxf[10], inboxf[10];           // compile-time indexed -> regs
#pragma unroll
        for (int x = 0; x < 10; ++x) {
            const int a = abs(x - p0x) + abs(x - p1x) - dx0;
            adxf[x] = (float)a;
            inboxf[x] = (a == 0) ? 1.f : 0.f;
        }

        // ---- pass 1: stream own 5 rows from LDS; keep sums + mask only ----
        const float2* __restrict__ rp2 = (const float2*)(sp + h * 50);
        float sum_h = 0.f, sc_h = 0.f, box_h = 0.f;
        uint64_t mword = 0;                   // own 50-bit mask, bit = i*10+x
#pragma unroll
        for (int i = 0; i < 5; ++i) {
            const int y = 5 * h + i;
            float v[10];
#pragma unroll
            for (int j2 = 0; j2 < 5; ++j2) {
                const float2 tt = rp2[i * 5 + j2];
                v[2 * j2] = tt.x; v[2 * j2 + 1] = tt.y;
            }
            const float rowacc = ((v[0]+v[1])+(v[2]+v[3])) +
                                 ((v[4]+v[5])+(v[6]+v[7])) + (v[8]+v[9]);
            sum_h += rowacc;
            const int ay = abs(y - p0y) + abs(y - p1y) - dy0;
            sc_h = fmaf((float)ay, rowacc, sc_h);
            float boxrow = 0.f;
            uint32_t rm = 0u;
#pragma unroll
            for (int x = 0; x < 10; ++x) {
                sc_h = fmaf(adxf[x], v[x], sc_h);
                boxrow = fmaf(inboxf[x], v[x], boxrow);
                // jnp.round half-to-even: for v in [0,1), round==1 <=> v>0.5
                rm |= (v[x] > 0.5f) ? (1u << x) : 0u;
            }
            box_h += (ay == 0) ? boxrow : 0.f;
            mword |= (uint64_t)rm << (10 * i);
        }
        const float sum_all = sum_h + __shfl_xor(sum_h, 1);
        const float sc      = sc_h  + __shfl_xor(sc_h, 1);
        const float boxSum  = box_h + __shfl_xor(box_h, 1);
        const uint64_t mo = (uint64_t)__shfl_xor((unsigned long long)mword, 1);
        const uint64_t mlo = h ? mo : mword;
        const uint64_t mhi = h ? mword : mo;

        // ---- flood fill: full board per lane (no per-iter pair sync) ----
        const uint64_t M50 = (1ull << 50) - 1;
        const uint64_t C0  = 0x10040100401ull;        // col-0 bit of 5 rows
        const uint64_t NC0 = M50 & ~C0;
        const uint64_t NC9 = M50 & ~(C0 << 9);
        uint64_t clo = 0, chi = 0;
        if (idx0 < 50) clo = 1ull << idx0; else chi = 1ull << (idx0 - 50);
#pragma unroll 1
        for (int it = 0; it < GH + GW; ++it) {        // cap 20 = reference
            const uint64_t hlo = clo | ((clo << 1) & NC0) | ((clo >> 1) & NC9);
            const uint64_t hhi = chi | ((chi << 1) & NC0) | ((chi >> 1) & NC9);
            uint64_t nlo = (hlo | (hlo << 10) | (hlo >> 10) | ((hhi & 0x3FFull) << 40)) & mlo;
            uint64_t nhi = (hhi | (hhi << 10) | (hhi >> 10) | (hlo >> 40)) & mhi;
            nlo |= clo; nhi |= chi;
            if (nlo == clo && nhi == chi) break;      // exit only at fixpoint
            clo = nlo; chi = nhi;
        }
        const int K = __popcll(clo) + __popcll(chi);

        // ---- S_T: re-stream own rows; bits via precomputed 5-bit fields ----
        // in_cl[y][x] = cluster bit (x*10+y); y = 5h+i -> pre-shift by 5h.
        // field[x] = bits i=0..4 for column x: (w >> 10*(x%5)) & 0x1F.
        const uint64_t wlo = clo >> (5 * h);
        const uint64_t whi = chi >> (5 * h);
        uint32_t fld[10];
#pragma unroll
        for (int x = 0; x < 10; ++x) {
            const uint64_t w = (x < 5) ? wlo : whi;        // compile-time sel
            fld[x] = (uint32_t)((w >> ((x % 5) * 10)) & 0x1Full);
        }
        float st_h = 0.f;
#pragma unroll
        for (int i = 0; i < 5; ++i) {
            float v[10];
#pragma unroll
            for (int j2 = 0; j2 < 5; ++j2) {
                const float2 tt = rp2[i * 5 + j2];
                v[2 * j2] = tt.x; v[2 * j2 + 1] = tt.y;
            }
#pragma unroll
            for (int x = 0; x < 10; ++x) {
                const uint32_t bit = (fld[x] >> i) & 1u;   // == r3's bit
                st_h = fmaf((float)bit, v[x], st_h);
            }
        }
        const float S_T = st_h + __shfl_xor(st_h, 1);

        // ---- argmin (own 5 rows, then pair merge; first-flat-index ties) ----
        int bestd = 1000, bidx = 0;
        const uint64_t cw = h ? chi : clo;
#pragma unroll
        for (int i = 0; i < 5; ++i) {
            const int y = 5 * h + i;
            const uint32_t rb = (uint32_t)((cw >> (10 * i)) & 0x3FFull);
            const uint32_t left  = rb & ((2u << p1x) - 1);
            const uint32_t right = rb >> p1x;
            const int dl = left  ? (p1x - (31 - __builtin_clz(left))) : 1000;
            const int dr = right ? __builtin_ctz(right) : 1000;
            int dx, xx;
            if (dl <= dr) { dx = dl; xx = p1x - dl; }      // tie -> smaller col
            else          { dx = dr; xx = p1x + dr; }
            const int d = abs(y - p1y) + dx;
            if (rb && d < bestd) { bestd = d; bidx = y * GW + xx; }
        }
        {   // pair merge; tie -> smaller flat index
            const int od = __shfl_xor(bestd, 1);
            const int oi = __shfl_xor(bidx, 1);
            if (od < bestd || (od == bestd && oi < bidx)) { bestd = od; bidx = oi; }
        }

        // ---- epilogue (replicated; only h==0 contributes) ----
        const bool better = bestd < base0;
        const int ny = better ? bidx / 10 : p0y;
        const int nx = better ? bidx % 10 : p0x;
        const int gap = min(base0, bestd);

        int by = ny, bx = nx, bg = gap;
        const int oy = p1y - ny, ox = p1x - nx;
        auto upd = [&](bool cond, int cy, int cx) {
            const int d = abs(cy - p1y) + abs(cx - p1x);
            if (cond && (d < bg)) { by = cy; bx = cx; bg = d; }
        };
        upd(ox < 0,                     ny,     nx - 1);
        upd((ox < 0) && (ny != 0),      ny - 1, nx - 1);
        upd((ox < 0) && (ny != GH - 1), ny + 1, nx - 1);
        upd(ox > 0,                     ny,     nx + 1);
        upd((ox > 0) && (ny != 0),      ny - 1, nx + 1);
        upd((ox > 0) && (ny != GH - 1), ny + 1, nx + 1);
        upd(oy < 0,                     ny - 1, nx);
        upd(oy > 0,                     ny + 1, nx);
        const int ncy = min(max(by, 0), GH - 1);
        const int ncx = min(max(bx, 0), GW - 1);
        const float rn = sp[ncy * GW + ncx];  // board still resident in LDS

        const float csf = (float)K;
        const float nboxf = (float)((dy0 + 1) * (dx0 + 1));
        const float loss_start = (2.f - (rs + re)) * 1000.f;
        const float lon = 5.f * csf + 15.f * sum_all - 20.f * S_T;
        const float single_cell = 0.5f * sc + 20.f * (nboxf - boxSum);
        const float cpen = 12.f * csf * S_T;
        const float gap_pen = (float)gap * 300.f * (1.f - rn);
        loss = loss_start + lon + single_cell + cpen + gap_pen;
        if (h != 0) loss = 0.f;                   // one contribution per sample
    }

    // ---- block reduction: wave shuffle -> LDS -> one atomic per block ----
#pragma unroll
    for (int off = 32; off > 0; off >>= 1)
        loss += __shfl_down(loss, off);
    if (lane == 0) wsum[wid] = loss;
    __syncthreads();
    if (tix == 0)
        atomicAdd(out, wsum[0] + wsum[1] + wsum[2] + wsum[3]);
}

extern "C" void kernel_launch(void* const* d_in, const int* in_sizes, int n_in,
                              void* d_out, int out_size, void* d_ws, size_t ws_size,
                              hipStream_t stream)
{
    const float* result = (const float*)d_in[0];
    const int* points   = (const int*)d_in[1];
    float* out = (float*)d_out;
    const int B = in_sizes[0] / 100;
    hipMemsetAsync(out, 0, sizeof(float), stream);   // harness poisons d_out
    const int block = 256;                            // 128 samples per block
    const int grid = (2 * B + block - 1) / block;
    custom_loss_kernel<<<grid, block, 0, stream>>>(result, points, out, B);
}

// Round 5
// 164.904 us; speedup vs baseline: 1.3242x; 1.3242x over previous
//
#include <hip/hip_runtime.h>
#include <cstdint>

#define GH 10
#define GW 10

// Round 10: wave-private LDS slices, staged by global_load_lds DMA (zero
// staging registers), zero block barriers, streamed board (no 50-float
// live range). Post-mortems: r4's float4 st[13] reg round-trip spilled
// (WRITE_SIZE 102MB = 208B/thread scratch); r7's strided loads cost ~1600
// line-touches/wave on the TA path (~20us); r3's register board lived in
// AGPRs (VGPR=52 + v_accvgpr tolls). This version has none of those:
// DMA writes LDS directly (13B->16B-wide, ~104 line-touches/wave), the
// only wait is a wave-level vmcnt(0) (same-wave producer/consumer), and
// compute streams the board from LDS twice (pass1: sums+mask; S_T pass
// re-streams after the flood fill). rs/re/rn stay LDS-hot. Arithmetic is
// bit-identical to r4/r0 (absmax 0). LDS 51.2KB -> 3 blocks/CU.
__device__ __forceinline__ void gld_lds16(const float4* g, float4* l)
{
    __builtin_amdgcn_global_load_lds(
        (const __attribute__((address_space(1))) void*)g,
        (__attribute__((address_space(3))) void*)l,
        16 /*bytes: literal*/, 0 /*offset*/, 0 /*aux*/);
}

__global__ __launch_bounds__(256, 3) void custom_loss_kernel(
    const float* __restrict__ result,
    const int* __restrict__ points,
    float* __restrict__ out,
    int B)
{
    __shared__ float lds[4 * 3200];           // 4 wave-private 12.8KB slices
    __shared__ float wsum[4];
    const int tix = threadIdx.x;
    const int lane = tix & 63;
    const int wid = tix >> 6;
    const int h = tix & 1;                    // half: rows 5h..5h+4
    const int t = lane >> 1;                  // sample within wave (0..31)

    const int s = blockIdx.x * 128 + wid * 32 + t;
    float* __restrict__ myLds = lds + wid * 3200;

    // ---- wave-private staging via LDS-DMA: 800 float4, fully coalesced ----
    {
        const size_t wb4 = ((size_t)blockIdx.x * 128 + wid * 32) * 25;
        const size_t total4 = (size_t)B * 25;
        const float4* __restrict__ g4 = (const float4*)result;
        float4* l4 = (float4*)myLds;
#pragma unroll
        for (int k = 0; k < 12; ++k) {        // 12 x 1KB; dest = base+lane*16
            size_t gi = wb4 + k * 64 + lane;
            if (gi >= total4) gi = total4 - 1;     // clamp: stay in-bounds,
            gld_lds16(g4 + gi, l4 + k * 64);       // all lanes active for DMA
        }
        if (lane < 32) {                      // 512B tail: plain ds_write
            size_t gi = wb4 + 768 + lane;
            if (gi >= total4) gi = total4 - 1;
            l4[768 + lane] = g4[gi];
        }
        // same-wave producer->consumer: wave-level waits, no barrier
        asm volatile("s_waitcnt vmcnt(0) lgkmcnt(0)" ::: "memory");
    }

    float loss = 0.f;
    if (s < B) {
        const int4 p = ((const int4*)points)[s];
        const int p0y = p.x, p0x = p.y, p1y = p.z, p1x = p.w;
        const int dy0 = abs(p0y - p1y), dx0 = abs(p0x - p1x);
        const int base0 = dy0 + dx0;
        const int idx0 = p0y * GW + p0x;
        const int idx1 = p1y * GW + p1x;

        const float* __restrict__ sp = myLds + t * 100;
        const float rs = sp[idx0];            // LDS gathers, board resident
        const float re = sp[idx1];

        float adxf[10], inboxf[10];           // compile-time indexed -> regs
#pragma unroll
        for (int x = 0; x < 10; ++x) {
            const int a = abs(x - p0x) + abs(x - p1x) - dx0;
            adxf[x] = (float)a;
            inboxf[x] = (a == 0) ? 1.f : 0.f;
        }

        // ---- pass 1: stream own 5 rows from LDS; keep sums + mask only ----
        const float2* __restrict__ rp2 = (const float2*)(sp + h * 50);
        float sum_h = 0.f, sc_h = 0.f, box_h = 0.f;
        uint64_t mword = 0;                   // own 50-bit mask, bit = i*10+x
#pragma unroll
        for (int i = 0; i < 5; ++i) {
            const int y = 5 * h + i;
            float v[10];
#pragma unroll
            for (int j2 = 0; j2 < 5; ++j2) {
                const float2 tt = rp2[i * 5 + j2];
                v[2 * j2] = tt.x; v[2 * j2 + 1] = tt.y;
            }
            const float rowacc = ((v[0]+v[1])+(v[2]+v[3])) +
                                 ((v[4]+v[5])+(v[6]+v[7])) + (v[8]+v[9]);
            sum_h += rowacc;
            const int ay = abs(y - p0y) + abs(y - p1y) - dy0;
            sc_h = fmaf((float)ay, rowacc, sc_h);
            float boxrow = 0.f;
            uint32_t rm = 0u;
#pragma unroll
            for (int x = 0; x < 10; ++x) {
                sc_h = fmaf(adxf[x], v[x], sc_h);
                boxrow = fmaf(inboxf[x], v[x], boxrow);
                // jnp.round half-to-even: for v in [0,1), round==1 <=> v>0.5
                rm |= (v[x] > 0.5f) ? (1u << x) : 0u;
            }
            box_h += (ay == 0) ? boxrow : 0.f;
            mword |= (uint64_t)rm << (10 * i);
        }
        const float sum_all = sum_h + __shfl_xor(sum_h, 1);
        const float sc      = sc_h  + __shfl_xor(sc_h, 1);
        const float boxSum  = box_h + __shfl_xor(box_h, 1);
        const uint64_t mo = (uint64_t)__shfl_xor((unsigned long long)mword, 1);
        const uint64_t mlo = h ? mo : mword;
        const uint64_t mhi = h ? mword : mo;

        // ---- flood fill: full board per lane (no per-iter pair sync) ----
        const uint64_t M50 = (1ull << 50) - 1;
        const uint64_t C0  = 0x10040100401ull;        // col-0 bit of 5 rows
        const uint64_t NC0 = M50 & ~C0;
        const uint64_t NC9 = M50 & ~(C0 << 9);
        uint64_t clo = 0, chi = 0;
        if (idx0 < 50) clo = 1ull << idx0; else chi = 1ull << (idx0 - 50);
#pragma unroll 1
        for (int it = 0; it < GH + GW; ++it) {        // cap 20 = reference
            const uint64_t hlo = clo | ((clo << 1) & NC0) | ((clo >> 1) & NC9);
            const uint64_t hhi = chi | ((chi << 1) & NC0) | ((chi >> 1) & NC9);
            uint64_t nlo = (hlo | (hlo << 10) | (hlo >> 10) | ((hhi & 0x3FFull) << 40)) & mlo;
            uint64_t nhi = (hhi | (hhi << 10) | (hhi >> 10) | (hlo >> 40)) & mhi;
            nlo |= clo; nhi |= chi;
            if (nlo == clo && nhi == chi) break;      // exit only at fixpoint
            clo = nlo; chi = nhi;
        }
        const int K = __popcll(clo) + __popcll(chi);

        // ---- S_T: re-stream own rows; bits via precomputed 5-bit fields ----
        // in_cl[y][x] = cluster bit (x*10+y); y = 5h+i -> pre-shift by 5h.
        const uint64_t wlo = clo >> (5 * h);
        const uint64_t whi = chi >> (5 * h);
        uint32_t fld[10];
#pragma unroll
        for (int x = 0; x < 10; ++x) {
            const uint64_t w = (x < 5) ? wlo : whi;        // compile-time sel
            fld[x] = (uint32_t)((w >> ((x % 5) * 10)) & 0x1Full);
        }
        float st_h = 0.f;
#pragma unroll
        for (int i = 0; i < 5; ++i) {
            float v[10];
#pragma unroll
            for (int j2 = 0; j2 < 5; ++j2) {
                const float2 tt = rp2[i * 5 + j2];
                v[2 * j2] = tt.x; v[2 * j2 + 1] = tt.y;
            }
#pragma unroll
            for (int x = 0; x < 10; ++x) {
                const uint32_t bit = (fld[x] >> i) & 1u;   // == r3's bit
                st_h = fmaf((float)bit, v[x], st_h);
            }
        }
        const float S_T = st_h + __shfl_xor(st_h, 1);

        // ---- argmin (own 5 rows, then pair merge; first-flat-index ties) ----
        int bestd = 1000, bidx = 0;
        const uint64_t cw = h ? chi : clo;
#pragma unroll
        for (int i = 0; i < 5; ++i) {
            const int y = 5 * h + i;
            const uint32_t rb = (uint32_t)((cw >> (10 * i)) & 0x3FFull);
            const uint32_t left  = rb & ((2u << p1x) - 1);
            const uint32_t right = rb >> p1x;
            const int dl = left  ? (p1x - (31 - __builtin_clz(left))) : 1000;
            const int dr = right ? __builtin_ctz(right) : 1000;
            int dx, xx;
            if (dl <= dr) { dx = dl; xx = p1x - dl; }      // tie -> smaller col
            else          { dx = dr; xx = p1x + dr; }
            const int d = abs(y - p1y) + dx;
            if (rb && d < bestd) { bestd = d; bidx = y * GW + xx; }
        }
        {   // pair merge; tie -> smaller flat index
            const int od = __shfl_xor(bestd, 1);
            const int oi = __shfl_xor(bidx, 1);
            if (od < bestd || (od == bestd && oi < bidx)) { bestd = od; bidx = oi; }
        }

        // ---- epilogue (replicated; only h==0 contributes) ----
        const bool better = bestd < base0;
        const int ny = better ? bidx / 10 : p0y;
        const int nx = better ? bidx % 10 : p0x;
        const int gap = min(base0, bestd);

        int by = ny, bx = nx, bg = gap;
        const int oy = p1y - ny, ox = p1x - nx;
        auto upd = [&](bool cond, int cy, int cx) {
            const int d = abs(cy - p1y) + abs(cx - p1x);
            if (cond && (d < bg)) { by = cy; bx = cx; bg = d; }
        };
        upd(ox < 0,                     ny,     nx - 1);
        upd((ox < 0) && (ny != 0),      ny - 1, nx - 1);
        upd((ox < 0) && (ny != GH - 1), ny + 1, nx - 1);
        upd(ox > 0,                     ny,     nx + 1);
        upd((ox > 0) && (ny != 0),      ny - 1, nx + 1);
        upd((ox > 0) && (ny != GH - 1), ny + 1, nx + 1);
        upd(oy < 0,                     ny - 1, nx);
        upd(oy > 0,                     ny + 1, nx);
        const int ncy = min(max(by, 0), GH - 1);
        const int ncx = min(max(bx, 0), GW - 1);
        const float rn = sp[ncy * GW + ncx];  // board still resident in LDS

        const float csf = (float)K;
        const float nboxf = (float)((dy0 + 1) * (dx0 + 1));
        const float loss_start = (2.f - (rs + re)) * 1000.f;
        const float lon = 5.f * csf + 15.f * sum_all - 20.f * S_T;
        const float single_cell = 0.5f * sc + 20.f * (nboxf - boxSum);
        const float cpen = 12.f * csf * S_T;
        const float gap_pen = (float)gap * 300.f * (1.f - rn);
        loss = loss_start + lon + single_cell + cpen + gap_pen;
        if (h != 0) loss = 0.f;                   // one contribution per sample
    }

    // ---- block reduction: wave shuffle -> LDS -> one atomic per block ----
#pragma unroll
    for (int off = 32; off > 0; off >>= 1)
        loss += __shfl_down(loss, off);
    if (lane == 0) wsum[wid] = loss;
    __syncthreads();
    if (tix == 0)
        atomicAdd(out, wsum[0] + wsum[1] + wsum[2] + wsum[3]);
}

extern "C" void kernel_launch(void* const* d_in, const int* in_sizes, int n_in,
                              void* d_out, int out_size, void* d_ws, size_t ws_size,
                              hipStream_t stream)
{
    const float* result = (const float*)d_in[0];
    const int* points   = (const int*)d_in[1];
    float* out = (float*)d_out;
    const int B = in_sizes[0] / 100;
    hipMemsetAsync(out, 0, sizeof(float), stream);   // harness poisons d_out
    const int block = 256;                            // 128 samples per block
    const int grid = (2 * B + block - 1) / block;
    custom_loss_kernel<<<grid, block, 0, stream>>>(result, points, out, B);
}